// Round 8
// baseline (593.379 us; speedup 1.0000x reference)
//
#include <hip/hip_runtime.h>

#define NPOST 100000
#define NUSER 50000
#define NENT  20000
#define NDTOT 420000
#define EACT  1350000   // active edges (contain excluded)
#define NSCANBLK 206
#define NT_AL 150000    // post + user nodes (ent branch is dead code)

typedef short short8 __attribute__((ext_vector_type(8)));
typedef float f32x4 __attribute__((ext_vector_type(4)));
typedef unsigned short ushort4v __attribute__((ext_vector_type(4)));

static __device__ __forceinline__ unsigned short f2bf(float x){
  union { float f; unsigned u; } v; v.f = x;
  unsigned r = v.u + 0x7FFF + ((v.u >> 16) & 1);
  return (unsigned short)(r >> 16);
}
static __device__ __forceinline__ float bf2f(unsigned short h){
  union { unsigned u; float f; } v; v.u = ((unsigned)h) << 16;
  return v.f;
}

struct EdgeMeta {
  const int* src[6];
  const int* dst[6];
  int E[6];
  int degoff[6];
};

// ---------------- merged prep kernel ----------------
struct PrepArgs {
  const float *Wp, *Wu, *We, *Wsrc, *Wdst, *asrc, *adst, *gatb;
  unsigned short *WpH, *WpL, *WuH, *WuL, *WeH, *WeL, *lbH, *lbL;
  float *weff_s, *weff_d, *bsum;
};

__global__ void k_prep(PrepArgs P){
  int idx = blockIdx.x * blockDim.x + threadIdx.x;
  if (idx < 49152){
    float x = P.Wp[idx];
    unsigned short h = f2bf(x);
    P.WpH[idx] = h; P.WpL[idx] = f2bf(x - bf2f(h));
  } else if (idx < 51200){
    int i = idx - 49152;
    float x = P.Wu[i];
    unsigned short h = f2bf(x);
    P.WuH[i] = h; P.WuL[i] = f2bf(x - bf2f(h));
  } else if (idx < 55296){
    int i = idx - 51200;
    float x = P.We[i];
    unsigned short h = f2bf(x);
    P.WeH[i] = h; P.WeL[i] = f2bf(x - bf2f(h));
  } else if (idx < 153600){
    int i = idx - 55296;
    const int off[6]  = {0, 24576, 40960, 49152, 73728, 90112};
    const int Ks[6]   = {384, 256, 128, 384, 256, 128};
    int seg = 5;
    #pragma unroll
    for (int s = 4; s >= 0; s--) if (i < off[s + 1]) seg = s;
    int l = seg / 3, type = seg % 3;
    int K = Ks[seg];
    int rem = i - off[seg];
    int n = rem / K, k = rem - n * K;
    int slot = k >> 7, head = (k >> 6) & 1, kk = k & 63;
    int rel;
    if (type == 0)      rel = (slot == 0) ? 0 : (slot == 1 ? 1 : 5);
    else if (type == 1) rel = (slot == 0) ? 3 : 4;
    else                rel = 2;
    int m = l * 6 + rel;
    float x = P.Wsrc[(size_t)m * 8192 + (head * 64 + n) * 64 + kk];
    unsigned short h = f2bf(x);
    P.lbH[i] = h; P.lbL[i] = f2bf(x - bf2f(h));
  } else if (idx < 156672){
    int i = idx - 153600;
    const float* W; const float* a; float* o; int j;
    if (i < 1536){ W = P.Wsrc; a = P.asrc; o = P.weff_s; j = i; }
    else         { W = P.Wdst; a = P.adst; o = P.weff_d; j = i - 1536; }
    int m = j >> 7;
    int rem = j & 127;
    int hh = rem >> 6, k = rem & 63;
    const float* Wm = W + (size_t)m * 8192;
    const float* am = a + (size_t)m * 128;
    float acc = 0.f;
    #pragma unroll 8
    for (int c = 0; c < 64; c++)
      acc += Wm[(hh * 64 + c) * 64 + k] * am[hh * 64 + c];
    o[j] = acc;
  } else if (idx < 157056){
    int i = idx - 156672;
    int c = i & 63;
    int lt = i >> 6;
    int l = lt / 3, t = lt % 3;
    float v;
    if (t == 0)      v = P.gatb[(l*6+0)*64+c] + P.gatb[(l*6+1)*64+c] + P.gatb[(l*6+5)*64+c];
    else if (t == 1) v = P.gatb[(l*6+3)*64+c] + P.gatb[(l*6+4)*64+c];
    else             v = P.gatb[(l*6+2)*64+c];
    P.bsum[lt * 64 + c] = v;
  }
}

// ---------------- CSR build (5 active relations; contain excluded) ----------------

__global__ void k_hist(EdgeMeta em, int* __restrict__ deg){
  const int map[5] = {0, 1, 3, 4, 5};
  int r = map[blockIdx.y];
  int e = blockIdx.x * blockDim.x + threadIdx.x;
  if (e >= em.E[r]) return;
  atomicAdd(&deg[em.degoff[r] + em.dst[r][e]], 1);
}

__global__ __launch_bounds__(256) void k_scanA(const int* __restrict__ deg,
                                               int* __restrict__ rowstart,
                                               int* __restrict__ blocksum){
  __shared__ int sums[256];
  int t = threadIdx.x;
  int base = blockIdx.x * 2048 + t * 8;
  int v[8]; int s = 0;
  #pragma unroll
  for (int i = 0; i < 8; i++){
    int j = base + i;
    v[i] = (j < NDTOT) ? deg[j] : 0;
    s += v[i];
  }
  sums[t] = s;
  __syncthreads();
  for (int off = 1; off < 256; off <<= 1){
    int x = (t >= off) ? sums[t - off] : 0;
    __syncthreads();
    sums[t] += x;
    __syncthreads();
  }
  int excl = (t > 0) ? sums[t - 1] : 0;
  if (t == 255) blocksum[blockIdx.x] = sums[255];
  int run = excl;
  #pragma unroll
  for (int i = 0; i < 8; i++){
    int j = base + i;
    if (j < NDTOT) rowstart[j] = run;
    run += v[i];
  }
}

__global__ __launch_bounds__(256) void k_scanB(int* __restrict__ blocksum){
  __shared__ int s[256];
  int t = threadIdx.x;
  s[t] = (t < NSCANBLK) ? blocksum[t] : 0;
  __syncthreads();
  for (int off = 1; off < 256; off <<= 1){
    int x = (t >= off) ? s[t - off] : 0;
    __syncthreads();
    s[t] += x;
    __syncthreads();
  }
  int excl = (t > 0) ? s[t - 1] : 0;
  if (t < NSCANBLK) blocksum[t] = excl;
}

__global__ void k_scanC(int* __restrict__ rowstart, const int* __restrict__ blocksum,
                        int* __restrict__ cursor){
  int j = blockIdx.x * blockDim.x + threadIdx.x;
  if (j < NDTOT){
    int v = rowstart[j] + blocksum[j >> 11];
    rowstart[j] = v;
    cursor[j] = v;
  }
  if (j == 0) rowstart[NDTOT] = EACT;
}

__global__ void k_scatter(EdgeMeta em, int* __restrict__ cursor, int* __restrict__ csr_src){
  const int map[5] = {0, 1, 3, 4, 5};
  int r = map[blockIdx.y];
  int e = blockIdx.x * blockDim.x + threadIdx.x;
  if (e >= em.E[r]) return;
  int d = em.dst[r][e];
  int w = em.degoff[r] + d;
  int pos = atomicAdd(&cursor[w], 1);
  csr_src[pos] = em.src[r][e];
}

// ---------------- merged attention-logit kernel ----------------
// als layout (src-side): publish@0, repost@50000, contain@100000(dead), interact@200000,
//                        follow@250000, similar@300000   (x2 floats per node)
// ald layout (dst-side): global row id = degoff[r] + node  (x2 floats per row)

struct AlArgs {
  const float *h0, *h1;          // post, user features
  const float *ws, *wd;          // weff_s/d + l*768
  float *als, *ald;
  int layer;
};

static __device__ __forceinline__ float2 dot2w(const float4* hr, const float* __restrict__ w){
  const float4* w0 = (const float4*)w;
  const float4* w1 = (const float4*)(w + 64);
  float a0 = 0.f, a1 = 0.f;
  #pragma unroll
  for (int q = 0; q < 16; q++){
    float4 v = hr[q];
    float4 x0 = w0[q], x1 = w1[q];
    a0 += v.x*x0.x + v.y*x0.y + v.z*x0.z + v.w*x0.w;
    a1 += v.x*x1.x + v.y*x1.y + v.z*x1.z + v.w*x1.w;
  }
  return make_float2(a0, a1);
}

__global__ __launch_bounds__(256) void k_al_all(AlArgs A){
  int i = blockIdx.x * blockDim.x + threadIdx.x;
  if (i >= NT_AL) return;
  float4 hr[16];
  if (i < NPOST){
    int n = i;
    const float4* hp = (const float4*)(A.h0 + (size_t)n * 64);
    #pragma unroll
    for (int q = 0; q < 16; q++) hr[q] = hp[q];
    *(float2*)(A.als + (size_t)(300000 + n) * 2) = dot2w(hr, A.ws + 5 * 128); // similar src
    *(float2*)(A.ald + (size_t)(0      + n) * 2) = dot2w(hr, A.wd + 0 * 128); // publish dst
    *(float2*)(A.ald + (size_t)(100000 + n) * 2) = dot2w(hr, A.wd + 1 * 128); // repost dst
    *(float2*)(A.ald + (size_t)(320000 + n) * 2) = dot2w(hr, A.wd + 5 * 128); // similar dst
  } else {
    int n = i - NPOST;
    const float4* hp = (const float4*)(A.h1 + (size_t)n * 64);
    #pragma unroll
    for (int q = 0; q < 16; q++) hr[q] = hp[q];
    *(float2*)(A.als + (size_t)(0      + n) * 2) = dot2w(hr, A.ws + 0 * 128); // publish src
    *(float2*)(A.als + (size_t)(50000  + n) * 2) = dot2w(hr, A.ws + 1 * 128); // repost src
    if (A.layer == 0){
      *(float2*)(A.als + (size_t)(200000 + n) * 2) = dot2w(hr, A.ws + 3 * 128); // interact src
      *(float2*)(A.als + (size_t)(250000 + n) * 2) = dot2w(hr, A.ws + 4 * 128); // follow src
      *(float2*)(A.ald + (size_t)(220000 + n) * 2) = dot2w(hr, A.wd + 3 * 128); // interact dst
      *(float2*)(A.ald + (size_t)(270000 + n) * 2) = dot2w(hr, A.wd + 4 * 128); // follow dst
    }
  }
}

// ---------------- fused aggregation + MFMA GEMM (+ optional classifier) ----------------
// 64-row tiles, 256 threads (4 waves). Phase 1: 16x 16-lane groups run the CSR
// aggregation with INLINE attention weights p = exp(leaky(als[src]+ald[row]))
// (identical expression/order as the old k_edgep -> bitwise identical), writing
// bf16 hi/lo A-fragments into a swizzled LDS tile. Phase 2: MFMA consumes the
// tile slot by slot (k ascending), B read from global (L2-hot).
// CLS=1 (layer-1 post job): instead of writing C, the relu'd tile goes to LDS
// and the classifier head (identical float4-dot expression as the old
// k_classifier) writes out[] directly.

static __device__ __forceinline__ int aswz(int row, int k){
  return row * 128 + ((((k >> 3) ^ (row & 7))) << 3) + (k & 7);
}

static __device__ __forceinline__ void edge_p(const int* __restrict__ csr_src,
                                              const float* __restrict__ als, float2 ad,
                                              int e, int& s_out, float& px, float& py){
  int sidx = csr_src[e];
  float2 as = *(const float2*)(als + (size_t)sidx * 2);
  float e0 = as.x + ad.x, e1 = as.y + ad.y;
  e0 = e0 > 0.f ? e0 : 0.2f * e0;
  e1 = e1 > 0.f ? e1 : 0.2f * e1;
  px = __expf(e0); py = __expf(e1);
  s_out = sidx;
}

static __device__ __forceinline__ void agg_row(const int* __restrict__ csr_src,
                                               const float* __restrict__ als, float2 ad,
                                               const float* __restrict__ h, int l16,
                                               int rs, int re,
                                               f32x4& a0, f32x4& a1, float& s0, float& s1){
  int e = rs;
  for (; e + 3 < re; e += 4){
    int sa, sb, sc, sd; float pax, pay, pbx, pby, pcx, pcy, pdx, pdy;
    edge_p(csr_src, als, ad, e,     sa, pax, pay);
    edge_p(csr_src, als, ad, e + 1, sb, pbx, pby);
    edge_p(csr_src, als, ad, e + 2, sc, pcx, pcy);
    edge_p(csr_src, als, ad, e + 3, sd, pdx, pdy);
    f32x4 ha = *(const f32x4*)(h + (size_t)sa * 64 + l16 * 4);
    f32x4 hb = *(const f32x4*)(h + (size_t)sb * 64 + l16 * 4);
    f32x4 hc = *(const f32x4*)(h + (size_t)sc * 64 + l16 * 4);
    f32x4 hd = *(const f32x4*)(h + (size_t)sd * 64 + l16 * 4);
    #pragma unroll
    for (int j = 0; j < 4; j++){ a0[j] = fmaf(pax, ha[j], a0[j]); a1[j] = fmaf(pay, ha[j], a1[j]); }
    s0 += pax; s1 += pay;
    #pragma unroll
    for (int j = 0; j < 4; j++){ a0[j] = fmaf(pbx, hb[j], a0[j]); a1[j] = fmaf(pby, hb[j], a1[j]); }
    s0 += pbx; s1 += pby;
    #pragma unroll
    for (int j = 0; j < 4; j++){ a0[j] = fmaf(pcx, hc[j], a0[j]); a1[j] = fmaf(pcy, hc[j], a1[j]); }
    s0 += pcx; s1 += pcy;
    #pragma unroll
    for (int j = 0; j < 4; j++){ a0[j] = fmaf(pdx, hd[j], a0[j]); a1[j] = fmaf(pdy, hd[j], a1[j]); }
    s0 += pdx; s1 += pdy;
  }
  for (; e + 1 < re; e += 2){
    int sa, sb; float pax, pay, pbx, pby;
    edge_p(csr_src, als, ad, e,     sa, pax, pay);
    edge_p(csr_src, als, ad, e + 1, sb, pbx, pby);
    f32x4 ha = *(const f32x4*)(h + (size_t)sa * 64 + l16 * 4);
    f32x4 hb = *(const f32x4*)(h + (size_t)sb * 64 + l16 * 4);
    #pragma unroll
    for (int j = 0; j < 4; j++){ a0[j] = fmaf(pax, ha[j], a0[j]); a1[j] = fmaf(pay, ha[j], a1[j]); }
    s0 += pax; s1 += pay;
    #pragma unroll
    for (int j = 0; j < 4; j++){ a0[j] = fmaf(pbx, hb[j], a0[j]); a1[j] = fmaf(pby, hb[j], a1[j]); }
    s0 += pbx; s1 += pby;
  }
  if (e < re){
    int sa; float pax, pay;
    edge_p(csr_src, als, ad, e, sa, pax, pay);
    f32x4 ha = *(const f32x4*)(h + (size_t)sa * 64 + l16 * 4);
    #pragma unroll
    for (int j = 0; j < 4; j++){ a0[j] = fmaf(pax, ha[j], a0[j]); a1[j] = fmaf(pay, ha[j], a1[j]); }
    s0 += pax; s1 += pay;
  }
}

struct FJob {
  const unsigned short *BH, *BL;
  const float *bias;
  float *C;
  int N, nslots, K;
  int wb0, wb1, wb2;     // global dst-row base per slot
  int ss0, ss1, ss2;     // src select per slot: 1 -> h1(user), 0 -> h0(post)
  int as0, as1, as2;     // als node-offset per slot
};
struct FArgs {
  const int *rowstart, *csr_src;
  const float *als, *ald;
  const float *h0, *h1;
  FJob j0, j1;
  int nb0;
  const float *cw1, *cb1, *cw2, *cb2;   // classifier (CLS=1 only)
  float *out;
};

template<int CLS>
__global__ __launch_bounds__(256) void k_fused(FArgs A){
  __shared__ __align__(16) unsigned short sbuf[2 * 64 * 128];   // 32 KB
  unsigned short* sAh = sbuf;
  unsigned short* sAl = sbuf + 64 * 128;
  int b = blockIdx.x;
  FJob J = (b < A.nb0) ? A.j0 : A.j1;
  int boff = (b < A.nb0) ? 0 : A.nb0;
  int r0 = (b - boff) * 64;
  int t = threadIdx.x;
  int w = t >> 6, lane = t & 63;
  int q = lane >> 4, m15 = lane & 15;
  int g2 = t >> 4, l16 = t & 15;
  int wr = w & 1, wc = w >> 1;
  f32x4 acc[2][2];
  #pragma unroll
  for (int i = 0; i < 2; i++)
    #pragma unroll
    for (int j = 0; j < 2; j++)
      acc[i][j] = (f32x4){0.f, 0.f, 0.f, 0.f};

  for (int s = 0; s < J.nslots; s++){
    int wbase = (s == 0) ? J.wb0 : ((s == 1) ? J.wb1 : J.wb2);
    int ssel  = (s == 0) ? J.ss0 : ((s == 1) ? J.ss1 : J.ss2);
    int aoff  = (s == 0) ? J.as0 : ((s == 1) ? J.as1 : J.as2);
    const float* h = ssel ? A.h1 : A.h0;
    const float* als = A.als + (size_t)aoff * 2;
    // ---- phase 1: aggregate 4 rows per group into LDS A tile ----
    for (int rr = g2; rr < 64; rr += 16){
      int grow = r0 + rr;
      int rs = 0, re = 0;
      float2 ad = make_float2(0.f, 0.f);
      if (grow < J.N){
        int wg = wbase + grow;
        rs = A.rowstart[wg];
        re = A.rowstart[wg + 1];
        ad = *(const float2*)(A.ald + (size_t)wg * 2);
      }
      f32x4 a0 = (f32x4){0.f,0.f,0.f,0.f};
      f32x4 a1 = (f32x4){0.f,0.f,0.f,0.f};
      float s0 = 0.f, s1 = 0.f;
      agg_row(A.csr_src, als, ad, h, l16, rs, re, a0, a1, s0, s1);
      float r0v = s0 > 0.f ? 0.5f / s0 : 0.f;
      float r1v = s1 > 0.f ? 0.5f / s1 : 0.f;
      ushort4v H0, H1, L0, L1;
      #pragma unroll
      for (int j = 0; j < 4; j++){
        float v0 = a0[j] * r0v;
        float v1 = a1[j] * r1v;
        unsigned short h0v = f2bf(v0); H0[j] = h0v; L0[j] = f2bf(v0 - bf2f(h0v));
        unsigned short h1v = f2bf(v1); H1[j] = h1v; L1[j] = f2bf(v1 - bf2f(h1v));
      }
      *(ushort4v*)(sAh + aswz(rr, l16 * 4))      = H0;
      *(ushort4v*)(sAh + aswz(rr, 64 + l16 * 4)) = H1;
      *(ushort4v*)(sAl + aswz(rr, l16 * 4))      = L0;
      *(ushort4v*)(sAl + aswz(rr, 64 + l16 * 4)) = L1;
    }
    __syncthreads();
    // ---- phase 2: MFMA over this slot's 4 k-chunks (k ascending) ----
    #pragma unroll
    for (int kc = 0; kc < 4; kc++){
      int gk = s * 128 + kc * 32;
      short8 ah[2], al_[2];
      #pragma unroll
      for (int i = 0; i < 2; i++){
        int mrow = wr * 32 + i * 16 + m15;
        ah[i]  = *(const short8*)(sAh + aswz(mrow, kc * 32 + q * 8));
        al_[i] = *(const short8*)(sAl + aswz(mrow, kc * 32 + q * 8));
      }
      #pragma unroll
      for (int j = 0; j < 2; j++){
        int bn = wc * 32 + j * 16 + m15;
        short8 bh = *(const short8*)(J.BH + (size_t)bn * J.K + gk + q * 8);
        short8 bl = *(const short8*)(J.BL + (size_t)bn * J.K + gk + q * 8);
        #pragma unroll
        for (int i = 0; i < 2; i++){
          acc[i][j] = __builtin_amdgcn_mfma_f32_16x16x32_bf16(ah[i],  bh, acc[i][j], 0, 0, 0);
          acc[i][j] = __builtin_amdgcn_mfma_f32_16x16x32_bf16(ah[i],  bl, acc[i][j], 0, 0, 0);
          acc[i][j] = __builtin_amdgcn_mfma_f32_16x16x32_bf16(al_[i], bh, acc[i][j], 0, 0, 0);
        }
      }
    }
    __syncthreads();
  }
  if (!CLS){
    // ---- epilogue: write relu'd C ----
    #pragma unroll
    for (int j = 0; j < 2; j++){
      int col = wc * 32 + j * 16 + m15;
      float bv = J.bias[col];
      #pragma unroll
      for (int i = 0; i < 2; i++){
        #pragma unroll
        for (int r = 0; r < 4; r++){
          int row = r0 + wr * 32 + i * 16 + q * 4 + r;
          if (row < J.N){
            float vv = acc[i][j][r] + bv;
            J.C[(size_t)row * 64 + col] = vv > 0.f ? vv : 0.f;
          }
        }
      }
    }
  } else {
    // ---- epilogue: relu'd tile -> LDS, then classifier head -> out ----
    float* ht  = (float*)sbuf;       // [64][68] floats, 16B-aligned rows
    float* w1s = ht + 64 * 68;       // 2048
    float* b1s = w1s + 2048;         // 32
    float* w2s = b1s + 32;           // 32
    #pragma unroll
    for (int j = 0; j < 2; j++){
      int col = wc * 32 + j * 16 + m15;
      float bv = J.bias[col];
      #pragma unroll
      for (int i = 0; i < 2; i++){
        #pragma unroll
        for (int r = 0; r < 4; r++){
          int lrow = wr * 32 + i * 16 + q * 4 + r;
          float vv = acc[i][j][r] + bv;
          ht[lrow * 68 + col] = vv > 0.f ? vv : 0.f;
        }
      }
    }
    for (int i = t; i < 2048; i += 256) w1s[i] = A.cw1[i];
    if (t < 32){ b1s[t] = A.cb1[t]; w2s[t] = A.cw2[t]; }
    __syncthreads();
    if (t < 64){
      int row = r0 + t;
      if (row < J.N){
        float4 hr[16];
        const float4* hp = (const float4*)(ht + t * 68);
        #pragma unroll
        for (int q16 = 0; q16 < 16; q16++) hr[q16] = hp[q16];
        float o = A.cb2[0];
        #pragma unroll 4
        for (int j = 0; j < 32; j++){
          float dacc = b1s[j];
          const float4* wr_ = (const float4*)(w1s + j * 64);
          #pragma unroll
          for (int q16 = 0; q16 < 16; q16++){
            float4 wv = wr_[q16]; float4 v = hr[q16];
            dacc += wv.x*v.x + wv.y*v.y + wv.z*v.z + wv.w*v.w;
          }
          dacc = dacc > 0.f ? dacc : 0.f;
          o += w2s[j] * dacc;
        }
        A.out[row] = o;
      }
    }
  }
}

// ---------------- MFMA GEMM (projections; 3 jobs per dispatch) ----------------

static __device__ __forceinline__ int swz(int row, int k){
  return row * 32 + ((((k >> 3) ^ ((row >> 2) & 3))) << 3) + (k & 7);
}

struct GemmJob {
  const float* A32;
  const unsigned short* AH; const unsigned short* AL;
  const unsigned short* BH; const unsigned short* BL;
  const float* bias; float* C;
  int N; int K;
};
struct GemmJobs { GemmJob j0, j1, j2; int nb0, nb1; };

template<int ASRC, int RELU>
__global__ __launch_bounds__(256) void k_mfgemm3(GemmJobs G){
  __shared__ __align__(16) unsigned short sAh[128 * 32];
  __shared__ __align__(16) unsigned short sAl[128 * 32];
  __shared__ __align__(16) unsigned short sBh[64 * 32];
  __shared__ __align__(16) unsigned short sBl[64 * 32];
  int b = blockIdx.x;
  GemmJob jb = G.j0;
  int boff = 0;
  if (b >= G.nb1){ jb = G.j2; boff = G.nb1; }
  else if (b >= G.nb0){ jb = G.j1; boff = G.nb0; }
  const float* A32 = jb.A32;
  const unsigned short* AH = jb.AH;
  const unsigned short* AL = jb.AL;
  const unsigned short* BH = jb.BH;
  const unsigned short* BL = jb.BL;
  int N = jb.N, K = jb.K;

  int t = threadIdx.x;
  int w = t >> 6, lane = t & 63;
  int q = lane >> 4, m15 = lane & 15;
  int r0 = (b - boff) * 128;
  f32x4 acc[2][4];
  #pragma unroll
  for (int i = 0; i < 2; i++)
    #pragma unroll
    for (int j = 0; j < 4; j++)
      acc[i][j] = (f32x4){0.f, 0.f, 0.f, 0.f};

  int arow = t >> 1, akb = (t & 1) * 16;
  int brow = t >> 2, bkb = (t & 3) * 8;

  for (int k0 = 0; k0 < K; k0 += 32){
    // ---- stage A ----
    int gr = r0 + arow;
    if (ASRC == 0){
      float v[16];
      if (gr < N){
        const float4* ap = (const float4*)(A32 + (size_t)gr * K + k0 + akb);
        #pragma unroll
        for (int i = 0; i < 4; i++){
          float4 f = ap[i];
          v[i*4+0] = f.x; v[i*4+1] = f.y; v[i*4+2] = f.z; v[i*4+3] = f.w;
        }
      } else {
        #pragma unroll
        for (int i = 0; i < 16; i++) v[i] = 0.f;
      }
      short8 h0, h1, l0, l1;
      #pragma unroll
      for (int i = 0; i < 8; i++){
        unsigned short hh = f2bf(v[i]);
        h0[i] = (short)hh; l0[i] = (short)f2bf(v[i] - bf2f(hh));
        unsigned short hj = f2bf(v[8+i]);
        h1[i] = (short)hj; l1[i] = (short)f2bf(v[8+i] - bf2f(hj));
      }
      *(short8*)(sAh + swz(arow, akb))     = h0;
      *(short8*)(sAh + swz(arow, akb + 8)) = h1;
      *(short8*)(sAl + swz(arow, akb))     = l0;
      *(short8*)(sAl + swz(arow, akb + 8)) = l1;
    } else {
      short8 h0 = {0,0,0,0,0,0,0,0}, h1 = {0,0,0,0,0,0,0,0};
      short8 l0 = {0,0,0,0,0,0,0,0}, l1 = {0,0,0,0,0,0,0,0};
      if (gr < N){
        const short8* hp = (const short8*)(AH + (size_t)gr * K + k0 + akb);
        const short8* lp = (const short8*)(AL + (size_t)gr * K + k0 + akb);
        h0 = hp[0]; h1 = hp[1];
        l0 = lp[0]; l1 = lp[1];
      }
      *(short8*)(sAh + swz(arow, akb))     = h0;
      *(short8*)(sAh + swz(arow, akb + 8)) = h1;
      *(short8*)(sAl + swz(arow, akb))     = l0;
      *(short8*)(sAl + swz(arow, akb + 8)) = l1;
    }
    // ---- stage B ----
    {
      short8 bh = *(const short8*)(BH + (size_t)brow * K + k0 + bkb);
      short8 bl = *(const short8*)(BL + (size_t)brow * K + k0 + bkb);
      *(short8*)(sBh + swz(brow, bkb)) = bh;
      *(short8*)(sBl + swz(brow, bkb)) = bl;
    }
    __syncthreads();
    // ---- fragments + MFMA ----
    short8 ah[2], al_[2];
    #pragma unroll
    for (int i = 0; i < 2; i++){
      int mrow = w * 32 + i * 16 + m15;
      ah[i]  = *(const short8*)(sAh + swz(mrow, q * 8));
      al_[i] = *(const short8*)(sAl + swz(mrow, q * 8));
    }
    #pragma unroll
    for (int j = 0; j < 4; j++){
      int bn = j * 16 + m15;
      short8 bh = *(const short8*)(sBh + swz(bn, q * 8));
      short8 bl = *(const short8*)(sBl + swz(bn, q * 8));
      #pragma unroll
      for (int i = 0; i < 2; i++){
        acc[i][j] = __builtin_amdgcn_mfma_f32_16x16x32_bf16(ah[i],  bh, acc[i][j], 0, 0, 0);
        acc[i][j] = __builtin_amdgcn_mfma_f32_16x16x32_bf16(ah[i],  bl, acc[i][j], 0, 0, 0);
        acc[i][j] = __builtin_amdgcn_mfma_f32_16x16x32_bf16(al_[i], bh, acc[i][j], 0, 0, 0);
      }
    }
    __syncthreads();
  }
  // ---- epilogue ----
  const float* bias = jb.bias;
  float* C = jb.C;
  #pragma unroll
  for (int j = 0; j < 4; j++){
    int col = j * 16 + m15;
    float bv = bias[col];
    #pragma unroll
    for (int i = 0; i < 2; i++){
      #pragma unroll
      for (int r = 0; r < 4; r++){
        int row = r0 + w * 32 + i * 16 + q * 4 + r;
        if (row < N){
          float vv = acc[i][j][r] + bv;
          if (RELU) vv = vv > 0.f ? vv : 0.f;
          C[(size_t)row * 64 + col] = vv;
        }
      }
    }
  }
}

// ---------------- host ----------------

static inline size_t align256(size_t x){ return (x + 255) & ~(size_t)255; }

extern "C" void kernel_launch(void* const* d_in, const int* in_sizes, int n_in,
                              void* d_out, int out_size, void* d_ws, size_t ws_size,
                              hipStream_t stream){
  (void)in_sizes; (void)n_in; (void)out_size; (void)ws_size;
  const float* x_post = (const float*)d_in[0];
  const float* x_user = (const float*)d_in[1];
  EdgeMeta em;
  for (int r = 0; r < 6; r++){
    em.src[r] = (const int*)d_in[3 + 2*r];
    em.dst[r] = (const int*)d_in[4 + 2*r];
  }
  const int Earr[6] = {100000, 200000, 200000, 400000, 400000, 250000};
  const int dgo[6]  = {0, 100000, 200000, 220000, 270000, 320000};
  for (int r = 0; r < 6; r++){ em.E[r] = Earr[r]; em.degoff[r] = dgo[r]; }

  const float* Wp   = (const float*)d_in[15]; const float* bp = (const float*)d_in[16];
  const float* Wu   = (const float*)d_in[17]; const float* bu = (const float*)d_in[18];
  const float* We   = (const float*)d_in[19];
  const float* Wsrc = (const float*)d_in[21];
  const float* Wdst = (const float*)d_in[22];
  const float* asrc = (const float*)d_in[23];
  const float* adst = (const float*)d_in[24];
  const float* gatb = (const float*)d_in[25];
  const float* cw1  = (const float*)d_in[26]; const float* cb1 = (const float*)d_in[27];
  const float* cw2  = (const float*)d_in[28]; const float* cb2 = (const float*)d_in[29];
  float* out = (float*)d_out;

  const int NN[2] = {NPOST, NUSER};

  // ---- workspace ----
  char* p = (char*)d_ws;
  auto alloc = [&](size_t bytes){ char* r = p; p += align256(bytes); return r; };
  float* hA[2]; float* hB[2];
  for (int i = 0; i < 2; i++) hA[i] = (float*)alloc((size_t)NN[i] * 64 * 4);
  for (int i = 0; i < 2; i++) hB[i] = (float*)alloc((size_t)NN[i] * 64 * 4);
  float* als = (float*)alloc((size_t)400000 * 2 * 4);
  float* ald = (float*)alloc((size_t)NDTOT * 2 * 4);
  float* weff_s = (float*)alloc(1536 * 4);
  float* weff_d = (float*)alloc(1536 * 4);
  unsigned short* WpH = (unsigned short*)alloc(768 * 64 * 2);
  unsigned short* WpL = (unsigned short*)alloc(768 * 64 * 2);
  unsigned short* WuH = (unsigned short*)alloc(32 * 64 * 2);
  unsigned short* WuL = (unsigned short*)alloc(32 * 64 * 2);
  unsigned short* WeH = (unsigned short*)alloc(64 * 64 * 2);
  unsigned short* WeL = (unsigned short*)alloc(64 * 64 * 2);
  unsigned short* lbH = (unsigned short*)alloc(98304 * 2);
  unsigned short* lbL = (unsigned short*)alloc(98304 * 2);
  float* bsum   = (float*)alloc(6 * 64 * 4);
  int* deg      = (int*)alloc((size_t)NDTOT * 4);
  int* rowstart = (int*)alloc((size_t)(NDTOT + 1) * 4);
  int* cursor   = (int*)alloc((size_t)NDTOT * 4);
  int* csr_src  = (int*)alloc((size_t)EACT * 4);
  int* blocksum = (int*)alloc((size_t)NSCANBLK * 4);

  // ---- CSR build (contain-free; rowstart layout keeps all NDTOT rows) ----
  hipMemsetAsync(deg, 0, (size_t)NDTOT * 4, stream);
  k_hist<<<dim3(1563, 5), 256, 0, stream>>>(em, deg);
  k_scanA<<<NSCANBLK, 256, 0, stream>>>(deg, rowstart, blocksum);
  k_scanB<<<1, 256, 0, stream>>>(blocksum);
  k_scanC<<<(NDTOT + 255) / 256, 256, 0, stream>>>(rowstart, blocksum, cursor);
  k_scatter<<<dim3(1563, 5), 256, 0, stream>>>(em, cursor, csr_src);

  // ---- merged weight prep ----
  PrepArgs P = {Wp, Wu, We, Wsrc, Wdst, asrc, adst, gatb,
                WpH, WpL, WuH, WuL, WeH, WeL, lbH, lbL,
                weff_s, weff_d, bsum};
  k_prep<<<614, 256, 0, stream>>>(P);

  // ---- input projections (post + user; ent is dead code) ----
  GemmJobs GP;
  GP.j0 = {x_post, nullptr, nullptr, WpH, WpL, bp, hA[0], NPOST, 768};
  GP.j1 = {x_user, nullptr, nullptr, WuH, WuL, bu, hA[1], NUSER, 32};
  GP.j2 = GP.j1;
  GP.nb0 = 782; GP.nb1 = 1173;
  k_mfgemm3<0, 0><<<1173, 256, 0, stream>>>(GP);

  const int segoff[6] = {0, 24576, 40960, 49152, 73728, 90112};  // (l,type) B offsets

  float* cur[2] = {hA[0], hA[1]};
  float* nxt[2] = {hB[0], hB[1]};

  for (int l = 0; l < 2; l++){
    AlArgs AA = {cur[0], cur[1], weff_s + l * 768, weff_d + l * 768, als, ald, l};
    k_al_all<<<(NT_AL + 255) / 256, 256, 0, stream>>>(AA);

    FArgs FA;
    FA.rowstart = rowstart; FA.csr_src = csr_src;
    FA.als = als; FA.ald = ald;
    FA.h0 = cur[0]; FA.h1 = cur[1];
    FA.cw1 = cw1; FA.cb1 = cb1; FA.cw2 = cw2; FA.cb2 = cb2; FA.out = out;
    // job0 (post): publish(als@0,user), repost(als@50000,user), similar(als@300000,post)
    FA.j0 = {lbH + segoff[l*3+0], lbL + segoff[l*3+0], bsum + (l*3+0) * 64, nxt[0],
             NPOST, 3, 384, 0, 100000, 320000, 1, 1, 0, 0, 50000, 300000};
    if (l == 0){
      // job1 (user): interact(als@200000), follow(als@250000)
      FA.j1 = {lbH + segoff[l*3+1], lbL + segoff[l*3+1], bsum + (l*3+1) * 64, nxt[1],
               NUSER, 2, 256, 220000, 270000, 0, 1, 1, 0, 200000, 250000, 0};
      FA.nb0 = 1563;
      k_fused<0><<<1563 + 782, 256, 0, stream>>>(FA);
    } else {
      FA.j1 = FA.j0;
      FA.nb0 = 1563;
      k_fused<1><<<1563, 256, 0, stream>>>(FA);
    }
    for (int i = 0; i < 2; i++){ float* tmp = cur[i]; cur[i] = nxt[i]; nxt[i] = tmp; }
  }
}

// Round 9
// 571.577 us; speedup vs baseline: 1.0381x; 1.0381x over previous
//
#include <hip/hip_runtime.h>

#define NPOST 100000
#define NUSER 50000
#define NENT  20000
#define NDTOT 420000
#define EACT  1350000   // active edges (contain excluded)
#define NSCANBLK 206
#define NT_AL 150000    // post + user nodes (ent branch is dead code)

typedef short short8 __attribute__((ext_vector_type(8)));
typedef float f32x4 __attribute__((ext_vector_type(4)));
typedef unsigned short ushort4v __attribute__((ext_vector_type(4)));

static __device__ __forceinline__ unsigned short f2bf(float x){
  union { float f; unsigned u; } v; v.f = x;
  unsigned r = v.u + 0x7FFF + ((v.u >> 16) & 1);
  return (unsigned short)(r >> 16);
}
static __device__ __forceinline__ float bf2f(unsigned short h){
  union { unsigned u; float f; } v; v.u = ((unsigned)h) << 16;
  return v.f;
}

struct EdgeMeta {
  const int* src[6];
  const int* dst[6];
  int E[6];
  int degoff[6];
};

struct PrepArgs {
  const float *Wp, *Wu, *We, *Wsrc, *Wdst, *asrc, *adst, *gatb;
  unsigned short *WpH, *WpL, *WuH, *WuL, *WeH, *WeL, *lbH, *lbL;
  float *weff_s, *weff_d, *bsum;
};

// ---------------- merged CSR-hist + weight-prep kernel ----------------
// blockIdx.y < 5: degree histogram for the 5 active relations.
// blockIdx.y == 5: weight prep (independent work, merged to save a dispatch).

__global__ void k_histprep(EdgeMeta em, int* __restrict__ deg, PrepArgs P){
  if (blockIdx.y < 5){
    const int map[5] = {0, 1, 3, 4, 5};
    int r = map[blockIdx.y];
    int e = blockIdx.x * blockDim.x + threadIdx.x;
    if (e >= em.E[r]) return;
    atomicAdd(&deg[em.degoff[r] + em.dst[r][e]], 1);
    return;
  }
  int idx = blockIdx.x * blockDim.x + threadIdx.x;
  if (idx < 49152){
    float x = P.Wp[idx];
    unsigned short h = f2bf(x);
    P.WpH[idx] = h; P.WpL[idx] = f2bf(x - bf2f(h));
  } else if (idx < 51200){
    int i = idx - 49152;
    float x = P.Wu[i];
    unsigned short h = f2bf(x);
    P.WuH[i] = h; P.WuL[i] = f2bf(x - bf2f(h));
  } else if (idx < 55296){
    int i = idx - 51200;
    float x = P.We[i];
    unsigned short h = f2bf(x);
    P.WeH[i] = h; P.WeL[i] = f2bf(x - bf2f(h));
  } else if (idx < 153600){
    int i = idx - 55296;
    const int off[6]  = {0, 24576, 40960, 49152, 73728, 90112};
    const int Ks[6]   = {384, 256, 128, 384, 256, 128};
    int seg = 5;
    #pragma unroll
    for (int s = 4; s >= 0; s--) if (i < off[s + 1]) seg = s;
    int l = seg / 3, type = seg % 3;
    int K = Ks[seg];
    int rem = i - off[seg];
    int n = rem / K, k = rem - n * K;
    int slot = k >> 7, head = (k >> 6) & 1, kk = k & 63;
    int rel;
    if (type == 0)      rel = (slot == 0) ? 0 : (slot == 1 ? 1 : 5);
    else if (type == 1) rel = (slot == 0) ? 3 : 4;
    else                rel = 2;
    int m = l * 6 + rel;
    float x = P.Wsrc[(size_t)m * 8192 + (head * 64 + n) * 64 + kk];
    unsigned short h = f2bf(x);
    P.lbH[i] = h; P.lbL[i] = f2bf(x - bf2f(h));
  } else if (idx < 156672){
    int i = idx - 153600;
    const float* W; const float* a; float* o; int j;
    if (i < 1536){ W = P.Wsrc; a = P.asrc; o = P.weff_s; j = i; }
    else         { W = P.Wdst; a = P.adst; o = P.weff_d; j = i - 1536; }
    int m = j >> 7;
    int rem = j & 127;
    int hh = rem >> 6, k = rem & 63;
    const float* Wm = W + (size_t)m * 8192;
    const float* am = a + (size_t)m * 128;
    float acc = 0.f;
    #pragma unroll 8
    for (int c = 0; c < 64; c++)
      acc += Wm[(hh * 64 + c) * 64 + k] * am[hh * 64 + c];
    o[j] = acc;
  } else if (idx < 157056){
    int i = idx - 156672;
    int c = i & 63;
    int lt = i >> 6;
    int l = lt / 3, t = lt % 3;
    float v;
    if (t == 0)      v = P.gatb[(l*6+0)*64+c] + P.gatb[(l*6+1)*64+c] + P.gatb[(l*6+5)*64+c];
    else if (t == 1) v = P.gatb[(l*6+3)*64+c] + P.gatb[(l*6+4)*64+c];
    else             v = P.gatb[(l*6+2)*64+c];
    P.bsum[lt * 64 + c] = v;
  }
}

// ---------------- CSR scan ----------------

__global__ __launch_bounds__(256) void k_scanA(const int* __restrict__ deg,
                                               int* __restrict__ rowstart,
                                               int* __restrict__ blocksum){
  __shared__ int sums[256];
  int t = threadIdx.x;
  int base = blockIdx.x * 2048 + t * 8;
  int v[8]; int s = 0;
  #pragma unroll
  for (int i = 0; i < 8; i++){
    int j = base + i;
    v[i] = (j < NDTOT) ? deg[j] : 0;
    s += v[i];
  }
  sums[t] = s;
  __syncthreads();
  for (int off = 1; off < 256; off <<= 1){
    int x = (t >= off) ? sums[t - off] : 0;
    __syncthreads();
    sums[t] += x;
    __syncthreads();
  }
  int excl = (t > 0) ? sums[t - 1] : 0;
  if (t == 255) blocksum[blockIdx.x] = sums[255];
  int run = excl;
  #pragma unroll
  for (int i = 0; i < 8; i++){
    int j = base + i;
    if (j < NDTOT) rowstart[j] = run;
    run += v[i];
  }
}

// scanB folded in: each block reduces the raw blocksums below its 2048-chunk
// (integer add is order-independent -> bitwise-identical rowstart/cursor).
__global__ __launch_bounds__(256) void k_scanC(const int* __restrict__ blocksum,
                                               int* __restrict__ rowstart,
                                               int* __restrict__ cursor){
  __shared__ int s[256];
  int t = threadIdx.x;
  int k = blockIdx.x >> 3;   // # of 2048-chunks before this block (<= 205)
  s[t] = (t < k) ? blocksum[t] : 0;
  __syncthreads();
  for (int off = 128; off > 0; off >>= 1){
    if (t < off) s[t] += s[t + off];
    __syncthreads();
  }
  int pre = s[0];
  int j = blockIdx.x * 256 + t;
  if (j < NDTOT){
    int v = rowstart[j] + pre;
    rowstart[j] = v;
    cursor[j] = v;
  }
  if (j == 0) rowstart[NDTOT] = EACT;
}

// also writes csr_row: global dst row id per CSR slot
__global__ void k_scatter(EdgeMeta em, int* __restrict__ cursor,
                          int* __restrict__ csr_src, int* __restrict__ csr_row){
  const int map[5] = {0, 1, 3, 4, 5};
  int r = map[blockIdx.y];
  int e = blockIdx.x * blockDim.x + threadIdx.x;
  if (e >= em.E[r]) return;
  int d = em.dst[r][e];
  int w = em.degoff[r] + d;
  int pos = atomicAdd(&cursor[w], 1);
  csr_src[pos] = em.src[r][e];
  csr_row[pos] = w;
}

// ---------------- merged attention-logit kernel ----------------
// als layout (src-side): publish@0, repost@50000, contain@100000(dead), interact@200000,
//                        follow@250000, similar@300000   (x2 floats per node)
// ald layout (dst-side): global row id = degoff[r] + node  (x2 floats per row)

struct AlArgs {
  const float *h0, *h1;          // post, user features
  const float *ws, *wd;          // weff_s/d + l*768
  float *als, *ald;
  int layer;
};

static __device__ __forceinline__ float2 dot2w(const float4* hr, const float* __restrict__ w){
  const float4* w0 = (const float4*)w;
  const float4* w1 = (const float4*)(w + 64);
  float a0 = 0.f, a1 = 0.f;
  #pragma unroll
  for (int q = 0; q < 16; q++){
    float4 v = hr[q];
    float4 x0 = w0[q], x1 = w1[q];
    a0 += v.x*x0.x + v.y*x0.y + v.z*x0.z + v.w*x0.w;
    a1 += v.x*x1.x + v.y*x1.y + v.z*x1.z + v.w*x1.w;
  }
  return make_float2(a0, a1);
}

__global__ __launch_bounds__(256) void k_al_all(AlArgs A){
  int i = blockIdx.x * blockDim.x + threadIdx.x;
  if (i >= NT_AL) return;
  float4 hr[16];
  if (i < NPOST){
    int n = i;
    const float4* hp = (const float4*)(A.h0 + (size_t)n * 64);
    #pragma unroll
    for (int q = 0; q < 16; q++) hr[q] = hp[q];
    *(float2*)(A.als + (size_t)(300000 + n) * 2) = dot2w(hr, A.ws + 5 * 128); // similar src
    *(float2*)(A.ald + (size_t)(0      + n) * 2) = dot2w(hr, A.wd + 0 * 128); // publish dst
    *(float2*)(A.ald + (size_t)(100000 + n) * 2) = dot2w(hr, A.wd + 1 * 128); // repost dst
    *(float2*)(A.ald + (size_t)(320000 + n) * 2) = dot2w(hr, A.wd + 5 * 128); // similar dst
  } else {
    int n = i - NPOST;
    const float4* hp = (const float4*)(A.h1 + (size_t)n * 64);
    #pragma unroll
    for (int q = 0; q < 16; q++) hr[q] = hp[q];
    *(float2*)(A.als + (size_t)(0      + n) * 2) = dot2w(hr, A.ws + 0 * 128); // publish src
    *(float2*)(A.als + (size_t)(50000  + n) * 2) = dot2w(hr, A.ws + 1 * 128); // repost src
    if (A.layer == 0){
      *(float2*)(A.als + (size_t)(200000 + n) * 2) = dot2w(hr, A.ws + 3 * 128); // interact src
      *(float2*)(A.als + (size_t)(250000 + n) * 2) = dot2w(hr, A.ws + 4 * 128); // follow src
      *(float2*)(A.ald + (size_t)(220000 + n) * 2) = dot2w(hr, A.wd + 3 * 128); // interact dst
      *(float2*)(A.ald + (size_t)(270000 + n) * 2) = dot2w(hr, A.wd + 4 * 128); // follow dst
    }
  }
}

// ---------------- edge-parallel attention weights (phase A) ----------------
// CSR edge-space (contain-free): publish [0,100000) repost [100000,300000)
// interact [300000,700000) follow [700000,1100000) similar [1100000,1350000)

struct EdgepArgs {
  const int *csr_src, *csr_row;
  const float *als, *ald;
  float2 *pcsr;
  int thr, off, nE;
};

__global__ __launch_bounds__(256) void k_edgep(EdgepArgs A){
  int e0 = blockIdx.x * blockDim.x + threadIdx.x;
  if (e0 >= A.nE) return;
  int e = e0 < A.thr ? e0 : e0 + A.off;
  int w = A.csr_row[e];
  int soffr;
  if      (w < 100000) soffr = 0;        // publish  (src: user)
  else if (w < 200000) soffr = 50000;    // repost   (src: user)
  else if (w < 270000) soffr = 200000;   // interact (src: user)
  else if (w < 320000) soffr = 250000;   // follow   (src: user)
  else                 soffr = 300000;   // similar  (src: post)
  int sidx = A.csr_src[e];
  float2 as = *(const float2*)(A.als + (size_t)(soffr + sidx) * 2);
  float2 ad = *(const float2*)(A.ald + (size_t)w * 2);
  float e0v = as.x + ad.x, e1v = as.y + ad.y;
  e0v = e0v > 0.f ? e0v : 0.2f * e0v;
  e1v = e1v > 0.f ? e1v : 0.2f * e1v;
  A.pcsr[e] = make_float2(__expf(e0v), __expf(e1v));
}

// ---------------- fused aggregation + MFMA GEMM (+ optional classifier) ----------------
// 64-row tiles, 256 threads (4 waves). Phase 1: 16x 16-lane groups run the CSR
// aggregation (pcsr precomputed -> no dependent random load in the edge chain),
// writing bf16 hi/lo A-fragments into a swizzled LDS tile. Phase 2: MFMA
// consumes the tile slot by slot (k ascending), B read from global (L2-hot).
// CLS=1 (layer-1 post job): relu'd tile -> LDS, classifier head -> out directly.

static __device__ __forceinline__ int aswz(int row, int k){
  return row * 128 + ((((k >> 3) ^ (row & 7))) << 3) + (k & 7);
}

static __device__ __forceinline__ void agg_row(const int* __restrict__ csr_src,
                                               const float2* __restrict__ pcsr,
                                               const float* __restrict__ h, int l16,
                                               int rs, int re,
                                               f32x4& a0, f32x4& a1, float& s0, float& s1){
  int e = rs;
  for (; e + 3 < re; e += 4){
    int sa = csr_src[e];
    int sb = csr_src[e + 1];
    int sc = csr_src[e + 2];
    int sd = csr_src[e + 3];
    float2 pa = pcsr[e];
    float2 pb = pcsr[e + 1];
    float2 pc = pcsr[e + 2];
    float2 pd = pcsr[e + 3];
    f32x4 ha = *(const f32x4*)(h + (size_t)sa * 64 + l16 * 4);
    f32x4 hb = *(const f32x4*)(h + (size_t)sb * 64 + l16 * 4);
    f32x4 hc = *(const f32x4*)(h + (size_t)sc * 64 + l16 * 4);
    f32x4 hd = *(const f32x4*)(h + (size_t)sd * 64 + l16 * 4);
    #pragma unroll
    for (int j = 0; j < 4; j++){ a0[j] = fmaf(pa.x, ha[j], a0[j]); a1[j] = fmaf(pa.y, ha[j], a1[j]); }
    s0 += pa.x; s1 += pa.y;
    #pragma unroll
    for (int j = 0; j < 4; j++){ a0[j] = fmaf(pb.x, hb[j], a0[j]); a1[j] = fmaf(pb.y, hb[j], a1[j]); }
    s0 += pb.x; s1 += pb.y;
    #pragma unroll
    for (int j = 0; j < 4; j++){ a0[j] = fmaf(pc.x, hc[j], a0[j]); a1[j] = fmaf(pc.y, hc[j], a1[j]); }
    s0 += pc.x; s1 += pc.y;
    #pragma unroll
    for (int j = 0; j < 4; j++){ a0[j] = fmaf(pd.x, hd[j], a0[j]); a1[j] = fmaf(pd.y, hd[j], a1[j]); }
    s0 += pd.x; s1 += pd.y;
  }
  for (; e + 1 < re; e += 2){
    int sa = csr_src[e];
    int sb = csr_src[e + 1];
    float2 pa = pcsr[e];
    float2 pb = pcsr[e + 1];
    f32x4 ha = *(const f32x4*)(h + (size_t)sa * 64 + l16 * 4);
    f32x4 hb = *(const f32x4*)(h + (size_t)sb * 64 + l16 * 4);
    #pragma unroll
    for (int j = 0; j < 4; j++){ a0[j] = fmaf(pa.x, ha[j], a0[j]); a1[j] = fmaf(pa.y, ha[j], a1[j]); }
    s0 += pa.x; s1 += pa.y;
    #pragma unroll
    for (int j = 0; j < 4; j++){ a0[j] = fmaf(pb.x, hb[j], a0[j]); a1[j] = fmaf(pb.y, hb[j], a1[j]); }
    s0 += pb.x; s1 += pb.y;
  }
  if (e < re){
    int sa = csr_src[e];
    float2 pa = pcsr[e];
    f32x4 ha = *(const f32x4*)(h + (size_t)sa * 64 + l16 * 4);
    #pragma unroll
    for (int j = 0; j < 4; j++){ a0[j] = fmaf(pa.x, ha[j], a0[j]); a1[j] = fmaf(pa.y, ha[j], a1[j]); }
    s0 += pa.x; s1 += pa.y;
  }
}

struct FJob {
  const unsigned short *BH, *BL;
  const float *bias;
  float *C;
  int N, nslots, K;
  int wb0, wb1, wb2;     // global dst-row base per slot
  int ss0, ss1, ss2;     // src select per slot: 1 -> h1(user), 0 -> h0(post)
};
struct FArgs {
  const int *rowstart, *csr_src;
  const float2 *pcsr;
  const float *h0, *h1;
  FJob j0, j1;
  int nb0;
  const float *cw1, *cb1, *cw2, *cb2;   // classifier (CLS=1 only)
  float *out;
};

template<int CLS>
__global__ __launch_bounds__(256) void k_fused(FArgs A){
  __shared__ __align__(16) unsigned short sbuf[2 * 64 * 128];   // 32 KB
  unsigned short* sAh = sbuf;
  unsigned short* sAl = sbuf + 64 * 128;
  int b = blockIdx.x;
  FJob J = (b < A.nb0) ? A.j0 : A.j1;
  int boff = (b < A.nb0) ? 0 : A.nb0;
  int r0 = (b - boff) * 64;
  int t = threadIdx.x;
  int w = t >> 6, lane = t & 63;
  int q = lane >> 4, m15 = lane & 15;
  int g2 = t >> 4, l16 = t & 15;
  int wr = w & 1, wc = w >> 1;
  f32x4 acc[2][2];
  #pragma unroll
  for (int i = 0; i < 2; i++)
    #pragma unroll
    for (int j = 0; j < 2; j++)
      acc[i][j] = (f32x4){0.f, 0.f, 0.f, 0.f};

  for (int s = 0; s < J.nslots; s++){
    int wbase = (s == 0) ? J.wb0 : ((s == 1) ? J.wb1 : J.wb2);
    int ssel  = (s == 0) ? J.ss0 : ((s == 1) ? J.ss1 : J.ss2);
    const float* h = ssel ? A.h1 : A.h0;
    // ---- phase 1: aggregate 4 rows per group into LDS A tile ----
    for (int rr = g2; rr < 64; rr += 16){
      int grow = r0 + rr;
      int rs = 0, re = 0;
      if (grow < J.N){
        int wg = wbase + grow;
        rs = A.rowstart[wg];
        re = A.rowstart[wg + 1];
      }
      f32x4 a0 = (f32x4){0.f,0.f,0.f,0.f};
      f32x4 a1 = (f32x4){0.f,0.f,0.f,0.f};
      float s0 = 0.f, s1 = 0.f;
      agg_row(A.csr_src, A.pcsr, h, l16, rs, re, a0, a1, s0, s1);
      float r0v = s0 > 0.f ? 0.5f / s0 : 0.f;
      float r1v = s1 > 0.f ? 0.5f / s1 : 0.f;
      ushort4v H0, H1, L0, L1;
      #pragma unroll
      for (int j = 0; j < 4; j++){
        float v0 = a0[j] * r0v;
        float v1 = a1[j] * r1v;
        unsigned short h0v = f2bf(v0); H0[j] = h0v; L0[j] = f2bf(v0 - bf2f(h0v));
        unsigned short h1v = f2bf(v1); H1[j] = h1v; L1[j] = f2bf(v1 - bf2f(h1v));
      }
      *(ushort4v*)(sAh + aswz(rr, l16 * 4))      = H0;
      *(ushort4v*)(sAh + aswz(rr, 64 + l16 * 4)) = H1;
      *(ushort4v*)(sAl + aswz(rr, l16 * 4))      = L0;
      *(ushort4v*)(sAl + aswz(rr, 64 + l16 * 4)) = L1;
    }
    __syncthreads();
    // ---- phase 2: MFMA over this slot's 4 k-chunks (k ascending) ----
    #pragma unroll
    for (int kc = 0; kc < 4; kc++){
      int gk = s * 128 + kc * 32;
      short8 ah[2], al_[2];
      #pragma unroll
      for (int i = 0; i < 2; i++){
        int mrow = wr * 32 + i * 16 + m15;
        ah[i]  = *(const short8*)(sAh + aswz(mrow, kc * 32 + q * 8));
        al_[i] = *(const short8*)(sAl + aswz(mrow, kc * 32 + q * 8));
      }
      #pragma unroll
      for (int j = 0; j < 2; j++){
        int bn = wc * 32 + j * 16 + m15;
        short8 bh = *(const short8*)(J.BH + (size_t)bn * J.K + gk + q * 8);
        short8 bl = *(const short8*)(J.BL + (size_t)bn * J.K + gk + q * 8);
        #pragma unroll
        for (int i = 0; i < 2; i++){
          acc[i][j] = __builtin_amdgcn_mfma_f32_16x16x32_bf16(ah[i],  bh, acc[i][j], 0, 0, 0);
          acc[i][j] = __builtin_amdgcn_mfma_f32_16x16x32_bf16(ah[i],  bl, acc[i][j], 0, 0, 0);
          acc[i][j] = __builtin_amdgcn_mfma_f32_16x16x32_bf16(al_[i], bh, acc[i][j], 0, 0, 0);
        }
      }
    }
    __syncthreads();
  }
  if (!CLS){
    // ---- epilogue: write relu'd C ----
    #pragma unroll
    for (int j = 0; j < 2; j++){
      int col = wc * 32 + j * 16 + m15;
      float bv = J.bias[col];
      #pragma unroll
      for (int i = 0; i < 2; i++){
        #pragma unroll
        for (int r = 0; r < 4; r++){
          int row = r0 + wr * 32 + i * 16 + q * 4 + r;
          if (row < J.N){
            float vv = acc[i][j][r] + bv;
            J.C[(size_t)row * 64 + col] = vv > 0.f ? vv : 0.f;
          }
        }
      }
    }
  } else {
    // ---- epilogue: relu'd tile -> LDS, then classifier head -> out ----
    float* ht  = (float*)sbuf;       // [64][68] floats, 16B-aligned rows
    float* w1s = ht + 64 * 68;       // 2048
    float* b1s = w1s + 2048;         // 32
    float* w2s = b1s + 32;           // 32
    #pragma unroll
    for (int j = 0; j < 2; j++){
      int col = wc * 32 + j * 16 + m15;
      float bv = J.bias[col];
      #pragma unroll
      for (int i = 0; i < 2; i++){
        #pragma unroll
        for (int r = 0; r < 4; r++){
          int lrow = wr * 32 + i * 16 + q * 4 + r;
          float vv = acc[i][j][r] + bv;
          ht[lrow * 68 + col] = vv > 0.f ? vv : 0.f;
        }
      }
    }
    for (int i = t; i < 2048; i += 256) w1s[i] = A.cw1[i];
    if (t < 32){ b1s[t] = A.cb1[t]; w2s[t] = A.cw2[t]; }
    __syncthreads();
    if (t < 64){
      int row = r0 + t;
      if (row < J.N){
        float4 hr[16];
        const float4* hp = (const float4*)(ht + t * 68);
        #pragma unroll
        for (int q16 = 0; q16 < 16; q16++) hr[q16] = hp[q16];
        float o = A.cb2[0];
        #pragma unroll 4
        for (int j = 0; j < 32; j++){
          float dacc = b1s[j];
          const float4* wr_ = (const float4*)(w1s + j * 64);
          #pragma unroll
          for (int q16 = 0; q16 < 16; q16++){
            float4 wv = wr_[q16]; float4 v = hr[q16];
            dacc += wv.x*v.x + wv.y*v.y + wv.z*v.z + wv.w*v.w;
          }
          dacc = dacc > 0.f ? dacc : 0.f;
          o += w2s[j] * dacc;
        }
        A.out[row] = o;
      }
    }
  }
}

// ---------------- MFMA GEMM (projections; 3 jobs per dispatch) ----------------

static __device__ __forceinline__ int swz(int row, int k){
  return row * 32 + ((((k >> 3) ^ ((row >> 2) & 3))) << 3) + (k & 7);
}

struct GemmJob {
  const float* A32;
  const unsigned short* AH; const unsigned short* AL;
  const unsigned short* BH; const unsigned short* BL;
  const float* bias; float* C;
  int N; int K;
};
struct GemmJobs { GemmJob j0, j1, j2; int nb0, nb1; };

template<int ASRC, int RELU>
__global__ __launch_bounds__(256) void k_mfgemm3(GemmJobs G){
  __shared__ __align__(16) unsigned short sAh[128 * 32];
  __shared__ __align__(16) unsigned short sAl[128 * 32];
  __shared__ __align__(16) unsigned short sBh[64 * 32];
  __shared__ __align__(16) unsigned short sBl[64 * 32];
  int b = blockIdx.x;
  GemmJob jb = G.j0;
  int boff = 0;
  if (b >= G.nb1){ jb = G.j2; boff = G.nb1; }
  else if (b >= G.nb0){ jb = G.j1; boff = G.nb0; }
  const float* A32 = jb.A32;
  const unsigned short* AH = jb.AH;
  const unsigned short* AL = jb.AL;
  const unsigned short* BH = jb.BH;
  const unsigned short* BL = jb.BL;
  int N = jb.N, K = jb.K;

  int t = threadIdx.x;
  int w = t >> 6, lane = t & 63;
  int q = lane >> 4, m15 = lane & 15;
  int r0 = (b - boff) * 128;
  f32x4 acc[2][4];
  #pragma unroll
  for (int i = 0; i < 2; i++)
    #pragma unroll
    for (int j = 0; j < 4; j++)
      acc[i][j] = (f32x4){0.f, 0.f, 0.f, 0.f};

  int arow = t >> 1, akb = (t & 1) * 16;
  int brow = t >> 2, bkb = (t & 3) * 8;

  for (int k0 = 0; k0 < K; k0 += 32){
    // ---- stage A ----
    int gr = r0 + arow;
    if (ASRC == 0){
      float v[16];
      if (gr < N){
        const float4* ap = (const float4*)(A32 + (size_t)gr * K + k0 + akb);
        #pragma unroll
        for (int i = 0; i < 4; i++){
          float4 f = ap[i];
          v[i*4+0] = f.x; v[i*4+1] = f.y; v[i*4+2] = f.z; v[i*4+3] = f.w;
        }
      } else {
        #pragma unroll
        for (int i = 0; i < 16; i++) v[i] = 0.f;
      }
      short8 h0, h1, l0, l1;
      #pragma unroll
      for (int i = 0; i < 8; i++){
        unsigned short hh = f2bf(v[i]);
        h0[i] = (short)hh; l0[i] = (short)f2bf(v[i] - bf2f(hh));
        unsigned short hj = f2bf(v[8+i]);
        h1[i] = (short)hj; l1[i] = (short)f2bf(v[8+i] - bf2f(hj));
      }
      *(short8*)(sAh + swz(arow, akb))     = h0;
      *(short8*)(sAh + swz(arow, akb + 8)) = h1;
      *(short8*)(sAl + swz(arow, akb))     = l0;
      *(short8*)(sAl + swz(arow, akb + 8)) = l1;
    } else {
      short8 h0 = {0,0,0,0,0,0,0,0}, h1 = {0,0,0,0,0,0,0,0};
      short8 l0 = {0,0,0,0,0,0,0,0}, l1 = {0,0,0,0,0,0,0,0};
      if (gr < N){
        const short8* hp = (const short8*)(AH + (size_t)gr * K + k0 + akb);
        const short8* lp = (const short8*)(AL + (size_t)gr * K + k0 + akb);
        h0 = hp[0]; h1 = hp[1];
        l0 = lp[0]; l1 = lp[1];
      }
      *(short8*)(sAh + swz(arow, akb))     = h0;
      *(short8*)(sAh + swz(arow, akb + 8)) = h1;
      *(short8*)(sAl + swz(arow, akb))     = l0;
      *(short8*)(sAl + swz(arow, akb + 8)) = l1;
    }
    // ---- stage B ----
    {
      short8 bh = *(const short8*)(BH + (size_t)brow * K + k0 + bkb);
      short8 bl = *(const short8*)(BL + (size_t)brow * K + k0 + bkb);
      *(short8*)(sBh + swz(brow, bkb)) = bh;
      *(short8*)(sBl + swz(brow, bkb)) = bl;
    }
    __syncthreads();
    // ---- fragments + MFMA ----
    short8 ah[2], al_[2];
    #pragma unroll
    for (int i = 0; i < 2; i++){
      int mrow = w * 32 + i * 16 + m15;
      ah[i]  = *(const short8*)(sAh + swz(mrow, q * 8));
      al_[i] = *(const short8*)(sAl + swz(mrow, q * 8));
    }
    #pragma unroll
    for (int j = 0; j < 4; j++){
      int bn = j * 16 + m15;
      short8 bh = *(const short8*)(sBh + swz(bn, q * 8));
      short8 bl = *(const short8*)(sBl + swz(bn, q * 8));
      #pragma unroll
      for (int i = 0; i < 2; i++){
        acc[i][j] = __builtin_amdgcn_mfma_f32_16x16x32_bf16(ah[i],  bh, acc[i][j], 0, 0, 0);
        acc[i][j] = __builtin_amdgcn_mfma_f32_16x16x32_bf16(ah[i],  bl, acc[i][j], 0, 0, 0);
        acc[i][j] = __builtin_amdgcn_mfma_f32_16x16x32_bf16(al_[i], bh, acc[i][j], 0, 0, 0);
      }
    }
    __syncthreads();
  }
  // ---- epilogue ----
  const float* bias = jb.bias;
  float* C = jb.C;
  #pragma unroll
  for (int j = 0; j < 4; j++){
    int col = j * 16 + m15;
    float bv = bias[col];
    #pragma unroll
    for (int i = 0; i < 2; i++){
      #pragma unroll
      for (int r = 0; r < 4; r++){
        int row = r0 + w * 32 + i * 16 + q * 4 + r;
        if (row < N){
          float vv = acc[i][j][r] + bv;
          if (RELU) vv = vv > 0.f ? vv : 0.f;
          C[(size_t)row * 64 + col] = vv;
        }
      }
    }
  }
}

// ---------------- host ----------------

static inline size_t align256(size_t x){ return (x + 255) & ~(size_t)255; }

extern "C" void kernel_launch(void* const* d_in, const int* in_sizes, int n_in,
                              void* d_out, int out_size, void* d_ws, size_t ws_size,
                              hipStream_t stream){
  (void)in_sizes; (void)n_in; (void)out_size; (void)ws_size;
  const float* x_post = (const float*)d_in[0];
  const float* x_user = (const float*)d_in[1];
  EdgeMeta em;
  for (int r = 0; r < 6; r++){
    em.src[r] = (const int*)d_in[3 + 2*r];
    em.dst[r] = (const int*)d_in[4 + 2*r];
  }
  const int Earr[6] = {100000, 200000, 200000, 400000, 400000, 250000};
  const int dgo[6]  = {0, 100000, 200000, 220000, 270000, 320000};
  for (int r = 0; r < 6; r++){ em.E[r] = Earr[r]; em.degoff[r] = dgo[r]; }

  const float* Wp   = (const float*)d_in[15]; const float* bp = (const float*)d_in[16];
  const float* Wu   = (const float*)d_in[17]; const float* bu = (const float*)d_in[18];
  const float* We   = (const float*)d_in[19];
  const float* Wsrc = (const float*)d_in[21];
  const float* Wdst = (const float*)d_in[22];
  const float* asrc = (const float*)d_in[23];
  const float* adst = (const float*)d_in[24];
  const float* gatb = (const float*)d_in[25];
  const float* cw1  = (const float*)d_in[26]; const float* cb1 = (const float*)d_in[27];
  const float* cw2  = (const float*)d_in[28]; const float* cb2 = (const float*)d_in[29];
  float* out = (float*)d_out;

  const int NN[2] = {NPOST, NUSER};

  // ---- workspace ----
  char* p = (char*)d_ws;
  auto alloc = [&](size_t bytes){ char* r = p; p += align256(bytes); return r; };
  float* hA[2]; float* hB[2];
  for (int i = 0; i < 2; i++) hA[i] = (float*)alloc((size_t)NN[i] * 64 * 4);
  for (int i = 0; i < 2; i++) hB[i] = (float*)alloc((size_t)NN[i] * 64 * 4);
  float* als = (float*)alloc((size_t)400000 * 2 * 4);
  float* ald = (float*)alloc((size_t)NDTOT * 2 * 4);
  float* weff_s = (float*)alloc(1536 * 4);
  float* weff_d = (float*)alloc(1536 * 4);
  unsigned short* WpH = (unsigned short*)alloc(768 * 64 * 2);
  unsigned short* WpL = (unsigned short*)alloc(768 * 64 * 2);
  unsigned short* WuH = (unsigned short*)alloc(32 * 64 * 2);
  unsigned short* WuL = (unsigned short*)alloc(32 * 64 * 2);
  unsigned short* WeH = (unsigned short*)alloc(64 * 64 * 2);
  unsigned short* WeL = (unsigned short*)alloc(64 * 64 * 2);
  unsigned short* lbH = (unsigned short*)alloc(98304 * 2);
  unsigned short* lbL = (unsigned short*)alloc(98304 * 2);
  float* bsum   = (float*)alloc(6 * 64 * 4);
  int* deg      = (int*)alloc((size_t)NDTOT * 4);
  int* rowstart = (int*)alloc((size_t)(NDTOT + 1) * 4);
  int* cursor   = (int*)alloc((size_t)NDTOT * 4);
  int* csr_src  = (int*)alloc((size_t)EACT * 4);
  int* csr_row  = (int*)alloc((size_t)EACT * 4);
  float2* pcsr  = (float2*)alloc((size_t)EACT * 8);
  int* blocksum = (int*)alloc((size_t)NSCANBLK * 4);

  // ---- CSR build + weight prep (merged where independent) ----
  hipMemsetAsync(deg, 0, (size_t)NDTOT * 4, stream);
  PrepArgs P = {Wp, Wu, We, Wsrc, Wdst, asrc, adst, gatb,
                WpH, WpL, WuH, WuL, WeH, WeL, lbH, lbL,
                weff_s, weff_d, bsum};
  k_histprep<<<dim3(1563, 6), 256, 0, stream>>>(em, deg, P);
  k_scanA<<<NSCANBLK, 256, 0, stream>>>(deg, rowstart, blocksum);
  k_scanC<<<(NDTOT + 255) / 256, 256, 0, stream>>>(blocksum, rowstart, cursor);
  k_scatter<<<dim3(1563, 5), 256, 0, stream>>>(em, cursor, csr_src, csr_row);

  // ---- input projections (post + user; ent is dead code) ----
  GemmJobs GP;
  GP.j0 = {x_post, nullptr, nullptr, WpH, WpL, bp, hA[0], NPOST, 768};
  GP.j1 = {x_user, nullptr, nullptr, WuH, WuL, bu, hA[1], NUSER, 32};
  GP.j2 = GP.j1;
  GP.nb0 = 782; GP.nb1 = 1173;
  k_mfgemm3<0, 0><<<1173, 256, 0, stream>>>(GP);

  const int segoff[6] = {0, 24576, 40960, 49152, 73728, 90112};  // (l,type) B offsets

  float* cur[2] = {hA[0], hA[1]};
  float* nxt[2] = {hB[0], hB[1]};

  for (int l = 0; l < 2; l++){
    AlArgs AA = {cur[0], cur[1], weff_s + l * 768, weff_d + l * 768, als, ald, l};
    k_al_all<<<(NT_AL + 255) / 256, 256, 0, stream>>>(AA);

    // layer 0: all active edges [0,1350000); layer 1: publish+repost+similar
    int nE  = (l == 0) ? EACT : 550000;
    int thr = (l == 0) ? EACT : 300000;
    int off = (l == 0) ? 0 : 800000;
    EdgepArgs EP = {csr_src, csr_row, als, ald, pcsr, thr, off, nE};
    k_edgep<<<(nE + 255) / 256, 256, 0, stream>>>(EP);

    FArgs FA;
    FA.rowstart = rowstart; FA.csr_src = csr_src; FA.pcsr = pcsr;
    FA.h0 = cur[0]; FA.h1 = cur[1];
    FA.cw1 = cw1; FA.cb1 = cb1; FA.cw2 = cw2; FA.cb2 = cb2; FA.out = out;
    // job0 (post): publish, repost (src user), similar (src post)
    FA.j0 = {lbH + segoff[l*3+0], lbL + segoff[l*3+0], bsum + (l*3+0) * 64, nxt[0],
             NPOST, 3, 384, 0, 100000, 320000, 1, 1, 0};
    if (l == 0){
      // job1 (user): interact, follow (src user)
      FA.j1 = {lbH + segoff[l*3+1], lbL + segoff[l*3+1], bsum + (l*3+1) * 64, nxt[1],
               NUSER, 2, 256, 220000, 270000, 0, 1, 1, 0};
      FA.nb0 = 1563;
      k_fused<0><<<1563 + 782, 256, 0, stream>>>(FA);
    } else {
      FA.j1 = FA.j0;
      FA.nb0 = 1563;
      k_fused<1><<<1563, 256, 0, stream>>>(FA);
    }
    for (int i = 0; i < 2; i++){ float* tmp = cur[i]; cur[i] = nxt[i]; nxt[i] = tmp; }
  }
}